// Round 19
// baseline (128.897 us; speedup 1.0000x reference)
//
#include <hip/hip_runtime.h>
#include <hip/hip_bf16.h>

#define DEVI __device__ __forceinline__

typedef float f32x4 __attribute__((ext_vector_type(4)));
typedef short bf16x8 __attribute__((ext_vector_type(8)));
typedef unsigned short ushort_t;

DEVI ushort_t f2bf(float x) {
  union { float f; unsigned u; } c; c.f = x;
  unsigned u = c.u;
  unsigned r = (u + 0x7fffu + ((u >> 16) & 1u)) >> 16;  // RNE
  return (ushort_t)r;
}

DEVI float bf2f(unsigned hw) {
  union { unsigned u; float f; } c; c.u = hw << 16; return c.f;
}

DEVI unsigned cvt_pk_bf16(float lo, float hi) {
  unsigned r;
  asm volatile("v_cvt_pk_bf16_f32 %0, %1, %2" : "=v"(r) : "v"(lo), "v"(hi));
  return r;
}

DEVI void gload16(const ushort_t* g, ushort_t* l) {
  __builtin_amdgcn_global_load_lds(
      (const __attribute__((address_space(1))) unsigned int*)g,
      (__attribute__((address_space(3))) unsigned int*)l, 16, 0, 0);
}

// ---- f32 -> bf16 conversion, weights only (X is fused into QKV GEMM) -------

__global__ __launch_bounds__(256)
void cvt_w_kernel(const float* __restrict__ w0, const float* __restrict__ w1,
                  const float* __restrict__ w2, const float* __restrict__ w3,
                  ushort_t* __restrict__ q0, ushort_t* __restrict__ q1,
                  ushort_t* __restrict__ q2, ushort_t* __restrict__ q3) {
  int z = blockIdx.y;
  int i = blockIdx.x * 256 + threadIdx.x;       // < 131072
  const float* in = (z == 0) ? w0 : (z == 1) ? w1 : (z == 2) ? w2 : w3;
  ushort_t* out = (z == 0) ? q0 : (z == 1) ? q1 : (z == 2) ? q2 : q3;
  const float4* p = (const float4*)in + (size_t)i * 2;
  float4 a = p[0], b = p[1];
  uint4 v;
  v.x = cvt_pk_bf16(a.x, a.y);
  v.y = cvt_pk_bf16(a.z, a.w);
  v.z = cvt_pk_bf16(b.x, b.y);
  v.w = cvt_pk_bf16(b.z, b.w);
  ((uint4*)out)[i] = v;
}

// ---- unified 128x128 GEMM: C[m][n] = sum_k A[m,k] * W[n,k] -----------------
// DOUBLE-buffered drain template (race-screened round 3/5): stage tile kt+1
// into buf^1 at the TOP of iteration kt (FWRITE f32-side + gload16 bf16-side
// + FLOAD of tile kt+2), compute from buf[cur], ONE full-drain __syncthreads
// at the bottom. Writes touch only buf^1, reads only buf[cur], one barrier
// between — f32 staging latency is hidden under the same iteration's MFMA.
// Transposed grid (x = big-operand panel -> XCD-local sharing).
// modes: 0 = Q (A=query f32, scaled), 1 = K (A=key f32), 2 = V^T (W=value
// f32; grid roles swapped), 3 = O-proj K-split half (both bf16).

__global__ __launch_bounds__(256)
void gemm128(const void* A0v, const void* A1v, const void* A2v,
             const void* W0v, const void* W1v, const void* W2v,
             void* __restrict__ O0, void* __restrict__ O1,
             void* __restrict__ O2, int mode_base, int nsteps, float qscale) {
  constexpr int K = 1024;
  int z = blockIdx.z;
  int mode = (mode_base == 3) ? 3 : mode_base + z;
  const void* Av = (z == 0) ? A0v : (z == 1) ? A1v : A2v;
  const void* Wv = (z == 0) ? W0v : (z == 1) ? W1v : W2v;
  void* Op = (z == 0) ? O0 : (z == 1) ? O1 : O2;
  if (mode == 3) {           // K-split: z picks the k-window, own partial buf
    Av = (const ushort_t*)A0v + z * 512;
    Wv = (const ushort_t*)W0v + z * 512;
    Op = z ? O1 : O0;
  }
  bool aF32 = (mode <= 1);   // block-uniform
  bool bF32 = (mode == 2);
  bool fused = aF32 || bF32;
  float scale = (mode == 0) ? qscale : 1.0f;
  // transposed mapping: x = big-operand panel, y = weight panel
  int m0 = (mode == 2) ? blockIdx.y * 128 : blockIdx.x * 128;
  int n0 = (mode == 2) ? blockIdx.x * 128 : blockIdx.y * 128;

  __shared__ __align__(16) ushort_t Asm[2][128 * 64];
  __shared__ __align__(16) ushort_t Bsm[2][128 * 64];

  int t = threadIdx.x;
  int lane = t & 63, wave = t >> 6;
  int wm = wave >> 1, wn = wave & 1;
  int col = lane & 15, g = lane >> 4;
  int lr = lane >> 3, lc = lane & 7;
  int cswz = col & 7;

  int rowA = m0 + wave * 32 + lr;
  int rowB = n0 + wave * 32 + lr;
  const ushort_t* aSrcB = (const ushort_t*)Av + (size_t)rowA * K + (lc ^ lr) * 8;
  const ushort_t* bSrcB = (const ushort_t*)Wv + (size_t)rowB * K + (lc ^ lr) * 8;
  // f32 side: read global chunk (lc^lr), write LDS chunk lc -> same image
  const float* fSrc = aF32
      ? ((const float*)Av + (size_t)rowA * K + (lc ^ lr) * 8)
      : ((const float*)Wv + (size_t)rowB * K + (lc ^ lr) * 8);
  int fOffBase = (wave * 32 + lr) * 64 + lc * 8;

  f32x4 z4 = {0.f, 0.f, 0.f, 0.f};
  f32x4 acc[4][4];
  for (int i = 0; i < 4; i++)
    for (int j = 0; j < 4; j++) acc[i][j] = z4;

  float4 fr[4][2];

#define FLOAD(koff) do {                                                   \
    _Pragma("unroll")                                                      \
    for (int i_ = 0; i_ < 4; i_++) {                                       \
      const float* p_ = fSrc + (size_t)(i_ * 8) * K + (koff);              \
      fr[i_][0] = *(const float4*)p_;                                      \
      fr[i_][1] = *(const float4*)(p_ + 4);                                \
    }                                                                      \
  } while (0)

#define FWRITE(buf) do {                                                   \
    ushort_t* fd_ = aF32 ? &Asm[buf][0] : &Bsm[buf][0];                    \
    _Pragma("unroll")                                                      \
    for (int i_ = 0; i_ < 4; i_++) {                                       \
      uint4 w_;                                                            \
      w_.x = cvt_pk_bf16(fr[i_][0].x, fr[i_][0].y);                        \
      w_.y = cvt_pk_bf16(fr[i_][0].z, fr[i_][0].w);                        \
      w_.z = cvt_pk_bf16(fr[i_][1].x, fr[i_][1].y);                        \
      w_.w = cvt_pk_bf16(fr[i_][1].z, fr[i_][1].w);                        \
      *(uint4*)(fd_ + fOffBase + i_ * 8 * 64) = w_;                        \
    }                                                                      \
  } while (0)

#define GLOADS(buf, koff) do {                                             \
    if (!aF32) {                                                           \
      _Pragma("unroll")                                                    \
      for (int i_ = 0; i_ < 4; i_++)                                       \
        gload16(aSrcB + (koff) + i_ * 8 * K,                               \
                &Asm[buf][(wave * 32 + i_ * 8) * 64]);                     \
    }                                                                      \
    if (!bF32) {                                                           \
      _Pragma("unroll")                                                    \
      for (int i_ = 0; i_ < 4; i_++)                                       \
        gload16(bSrcB + (koff) + i_ * 8 * K,                               \
                &Bsm[buf][(wave * 32 + i_ * 8) * 64]);                     \
    }                                                                      \
  } while (0)

  // prologue: tile 0 into buf0; prefetch f32 tile 1 into regs
  if (fused) { FLOAD(0); FWRITE(0); }
  GLOADS(0, 0);
  if (fused && nsteps > 1) FLOAD(64);
  __syncthreads();                     // buf0 ready (full vmcnt/lgkm drain)

  for (int kt = 0; kt < nsteps; ++kt) {
    int cur = kt & 1;
    if (kt + 1 < nsteps) {             // stage tile kt+1 into buf^1 (top)
      if (fused) FWRITE(cur ^ 1);      // fr holds tile kt+1 (drained by sync)
      GLOADS(cur ^ 1, (kt + 1) * 64);
      if (fused && kt + 2 < nsteps) FLOAD((kt + 2) * 64);
    }
#pragma unroll
    for (int kk = 0; kk < 2; ++kk) {
      bf16x8 af[4], bfr[4];
#pragma unroll
      for (int mi = 0; mi < 4; mi++) {
        int row = wm * 64 + mi * 16 + col;
        af[mi] = *(const bf16x8*)(&Asm[cur][0] + row * 64 +
                                  (((kk * 4 + g) ^ cswz) * 8));
      }
#pragma unroll
      for (int ni = 0; ni < 4; ni++) {
        int row = wn * 64 + ni * 16 + col;
        bfr[ni] = *(const bf16x8*)(&Bsm[cur][0] + row * 64 +
                                   (((kk * 4 + g) ^ cswz) * 8));
      }
      __builtin_amdgcn_s_setprio(1);
#pragma unroll
      for (int mi = 0; mi < 4; mi++)
#pragma unroll
        for (int ni = 0; ni < 4; ni++)
          acc[mi][ni] = __builtin_amdgcn_mfma_f32_16x16x32_bf16(af[mi], bfr[ni],
                                                                acc[mi][ni], 0, 0, 0);
      __builtin_amdgcn_s_setprio(0);
    }
    __syncthreads();   // drains gloads+FLOADs+ds_writes+reads; full fence
  }

  // epilogue: C row m = m0+wm*64+mi*16+g*4+r, col n = n0+wn*64+ni*16+col
#pragma unroll
  for (int mi = 0; mi < 4; mi++)
#pragma unroll
    for (int ni = 0; ni < 4; ni++)
#pragma unroll
      for (int r = 0; r < 4; r++) {
        int m = m0 + wm * 64 + mi * 16 + g * 4 + r;
        int n = n0 + wn * 64 + ni * 16 + col;
        float v = acc[mi][ni][r] * scale;
        if (mode <= 1) {          // [B,H,S,64]: m=token, n=h*64+d
          int b = m >> 11, s = m & 2047, h = n >> 6, d = n & 63;
          ((ushort_t*)Op)[(((size_t)(b * 16 + h) * 2048 + s) * 64) + d] = f2bf(v);
        } else if (mode == 2) {   // V^T [B,H,64,S]: m=h*64+d, n=token
          int h = m >> 6, d = m & 63, b = n >> 11, s = n & 2047;
          ((ushort_t*)Op)[(((size_t)(b * 16 + h) * 64 + d) * 2048) + s] = f2bf(v);
        } else {                  // bf16 partial [M,1024]
          ((ushort_t*)Op)[(size_t)m * 1024 + n] = f2bf(v);
        }
      }
#undef FLOAD
#undef FWRITE
#undef GLOADS
}

// ---- flash attention — KV-split x2, permuted-K staging, lane-local P --------
// Round-16 kernel ((256,3) proven 44.5 us) + packed 4B epilogue stores.

__global__ __launch_bounds__(256, 3)
void attn_kernel(const ushort_t* __restrict__ Qh, const ushort_t* __restrict__ Kh,
                 const ushort_t* __restrict__ Vt,
                 ushort_t* __restrict__ op0, ushort_t* __restrict__ op1,
                 float* __restrict__ lp0, float* __restrict__ lp1) {
  int bh = blockIdx.x;   // b*16+h  (XCD-co-located)
  int qt = blockIdx.y;   // q tile of 128
  int sp = blockIdx.z;   // key split (0: keys 0..1023, 1: 1024..2047)
  int t = threadIdx.x, lane = t & 63, wave = t >> 6;
  int col = lane & 15, g = lane >> 4;
  int lr = lane >> 3, lc = lane & 7;
  int cswz = col & 7;
  int q0 = qt * 128 + wave * 32;
  int kbase = sp * 1024;
  ushort_t* opart = sp ? op1 : op0;
  float* lpart = sp ? lp1 : lp0;

  const ushort_t* Qp = Qh + (size_t)bh * 2048 * 64;
  const ushort_t* Kp = Kh + (size_t)bh * 2048 * 64;
  const ushort_t* Vp = Vt + (size_t)bh * 64 * 2048;  // [64 d][2048 k]

  __shared__ __align__(16) ushort_t Ksm[2][64 * 64];
  __shared__ __align__(16) ushort_t Vsm[2][64 * 64];

  // K row permutation: slot -> key (bits: s=a<<5|b<<4|g<<2|r -> a<<5|g<<3|b<<2|r)
  int slot0 = wave * 16 + lr;
  int slot1 = slot0 + 8;
  int key0 = (slot0 & 0x20) | ((slot0 & 0x0C) << 1) | ((slot0 & 0x10) >> 2) | (slot0 & 3);
  int key1 = (slot1 & 0x20) | ((slot1 & 0x0C) << 1) | ((slot1 & 0x10) >> 2) | (slot1 & 3);

  const ushort_t* kSrc0 = Kp + (size_t)key0 * 64 + (lc ^ lr) * 8;
  const ushort_t* kSrc1 = Kp + (size_t)key1 * 64 + (lc ^ lr) * 8;
  const ushort_t* vSrc = Vp + (size_t)(wave * 16 + lr) * 2048 + (lc ^ lr) * 8;

#define ATTN_STAGE(buf, k0) do { \
    gload16(kSrc0 + (size_t)(k0) * 64, &Ksm[buf][wave * 1024]);        \
    gload16(kSrc1 + (size_t)(k0) * 64, &Ksm[buf][wave * 1024 + 512]);  \
    gload16(vSrc + (k0),               &Vsm[buf][wave * 1024]);        \
    gload16(vSrc + (k0) + 16384,       &Vsm[buf][wave * 1024 + 512]);  \
  } while (0)

  bf16x8 qa0 = *(const bf16x8*)(Qp + (size_t)(q0 + col) * 64 + g * 8);
  bf16x8 qa1 = *(const bf16x8*)(Qp + (size_t)(q0 + col) * 64 + 32 + g * 8);
  bf16x8 qb0 = *(const bf16x8*)(Qp + (size_t)(q0 + 16 + col) * 64 + g * 8);
  bf16x8 qb1 = *(const bf16x8*)(Qp + (size_t)(q0 + 16 + col) * 64 + 32 + g * 8);

  f32x4 z4 = {0.f, 0.f, 0.f, 0.f};
  f32x4 oa[4], ob[4];
  for (int i = 0; i < 4; i++) { oa[i] = z4; ob[i] = z4; }
  f32x4 la = z4, lb = z4;   // per-lane partial denominators

  ATTN_STAGE(0, kbase);
  __syncthreads();                       // buf0 ready

  for (int it = 0; it < 16; ++it) {
    int cur = it & 1;
    int k0 = kbase + it * 64;
    if (it < 15) ATTN_STAGE(cur ^ 1, k0 + 64);  // prefetch next tile

    const ushort_t* Ks = Ksm[cur];
    const ushort_t* Vs = Vsm[cur];

    // QK^T (swapped): sX[kt][r] = exp2-domain score(slot = kt*16+4g+r, q)
    f32x4 sa[4], sb[4];
#pragma unroll
    for (int kt = 0; kt < 4; kt++) {
      int off = (kt * 16 + col) * 64 + ((g ^ cswz) * 8);
      bf16x8 kf0 = *(const bf16x8*)(Ks + off);
      bf16x8 kf1 = *(const bf16x8*)(Ks + (off ^ 32));
      f32x4 a = z4, b = z4;
      __builtin_amdgcn_s_setprio(1);
      a = __builtin_amdgcn_mfma_f32_16x16x32_bf16(kf0, qa0, a, 0, 0, 0);
      a = __builtin_amdgcn_mfma_f32_16x16x32_bf16(kf1, qa1, a, 0, 0, 0);
      b = __builtin_amdgcn_mfma_f32_16x16x32_bf16(kf0, qb0, b, 0, 0, 0);
      b = __builtin_amdgcn_mfma_f32_16x16x32_bf16(kf1, qb1, b, 0, 0, 0);
      __builtin_amdgcn_s_setprio(0);
      sa[kt] = a; sb[kt] = b;
    }

    // exp2 numerators; packed u32s are, in order, exactly the PV B-fragments
    unsigned pka[8], pkb[8];
#pragma unroll
    for (int kt = 0; kt < 4; kt++) {
      float a0 = __builtin_amdgcn_exp2f(sa[kt][0]);
      float a1 = __builtin_amdgcn_exp2f(sa[kt][1]);
      float a2 = __builtin_amdgcn_exp2f(sa[kt][2]);
      float a3 = __builtin_amdgcn_exp2f(sa[kt][3]);
      la[0] += a0; la[1] += a1; la[2] += a2; la[3] += a3;
      pka[2 * kt]     = cvt_pk_bf16(a0, a1);
      pka[2 * kt + 1] = cvt_pk_bf16(a2, a3);
      float b0 = __builtin_amdgcn_exp2f(sb[kt][0]);
      float b1 = __builtin_amdgcn_exp2f(sb[kt][1]);
      float b2 = __builtin_amdgcn_exp2f(sb[kt][2]);
      float b3 = __builtin_amdgcn_exp2f(sb[kt][3]);
      lb[0] += b0; lb[1] += b1; lb[2] += b2; lb[3] += b3;
      pkb[2 * kt]     = cvt_pk_bf16(b0, b1);
      pkb[2 * kt + 1] = cvt_pk_bf16(b2, b3);
    }

    // PV: O^T += mfma(V^T, P^T), P fragment straight from registers
#pragma unroll
    for (int kk = 0; kk < 2; kk++) {
      union { uint4 u; bf16x8 f; } ua, ub;
      ua.u.x = pka[4 * kk];     ua.u.y = pka[4 * kk + 1];
      ua.u.z = pka[4 * kk + 2]; ua.u.w = pka[4 * kk + 3];
      ub.u.x = pkb[4 * kk];     ub.u.y = pkb[4 * kk + 1];
      ub.u.z = pkb[4 * kk + 2]; ub.u.w = pkb[4 * kk + 3];
      __builtin_amdgcn_s_setprio(1);
#pragma unroll
      for (int dt = 0; dt < 4; dt++) {
        bf16x8 vf = *(const bf16x8*)(Vs + (dt * 16 + col) * 64 +
                                     (((kk * 4 + g) ^ cswz) * 8));
        oa[dt] = __builtin_amdgcn_mfma_f32_16x16x32_bf16(vf, ua.f, oa[dt], 0, 0, 0);
        ob[dt] = __builtin_amdgcn_mfma_f32_16x16x32_bf16(vf, ub.f, ob[dt], 0, 0, 0);
      }
      __builtin_amdgcn_s_setprio(0);
    }
    __syncthreads();   // drains vmcnt(0) (next K/V buf written) + lgkm; fence
  }
#undef ATTN_STAGE

  float lva = (la[0] + la[1]) + (la[2] + la[3]);
  lva += __shfl_xor(lva, 16);
  lva += __shfl_xor(lva, 32);
  float lvb = (lb[0] + lb[1]) + (lb[2] + lb[3]);
  lvb += __shfl_xor(lvb, 16);
  lvb += __shfl_xor(lvb, 32);
  if (g == 0) {                                 // lanes 0..15 write l
    lpart[(size_t)bh * 2048 + q0 + col] = lva;
    lpart[(size_t)bh * 2048 + q0 + 16 + col] = lvb;
  }
  int b = bh >> 4, h = bh & 15;
  // packed epilogue: d pairs -> one 4B store
#pragma unroll
  for (int dt = 0; dt < 4; dt++)
#pragma unroll
    for (int rp = 0; rp < 2; rp++) {
      int d = dt * 16 + g * 4 + rp * 2;
      unsigned pa = cvt_pk_bf16(oa[dt][rp * 2], oa[dt][rp * 2 + 1]);
      unsigned pb = cvt_pk_bf16(ob[dt][rp * 2], ob[dt][rp * 2 + 1]);
      *(unsigned*)(opart + ((size_t)(b * 2048 + q0 + col)) * 1024 + h * 64 + d) = pa;
      *(unsigned*)(opart + ((size_t)(b * 2048 + q0 + 16 + col)) * 1024 + h * 64 + d) = pb;
    }
}

// ---- attn partial combine: ctx = (o0 + o1) / (l0 + l1) ---------------------

__global__ __launch_bounds__(256)
void attn_reduce(const ushort_t* __restrict__ o0, const ushort_t* __restrict__ o1,
                 const float* __restrict__ l0, const float* __restrict__ l1,
                 ushort_t* __restrict__ ctx) {
  int m = blockIdx.x;                  // token 0..4095
  int t = threadIdx.x;                 // 4 bf16 elems each
  int b = m >> 11, q = m & 2047;
  int h = t >> 4;                      // (t*4) >> 6
  size_t li = (size_t)(b * 16 + h) * 2048 + q;
  float inv = 1.0f / (l0[li] + l1[li]);
  uint2 a = ((const uint2*)(o0 + (size_t)m * 1024))[t];
  uint2 c = ((const uint2*)(o1 + (size_t)m * 1024))[t];
  float x0 = (bf2f(a.x & 0xffffu) + bf2f(c.x & 0xffffu)) * inv;
  float x1 = (bf2f(a.x >> 16)     + bf2f(c.x >> 16))     * inv;
  float x2 = (bf2f(a.y & 0xffffu) + bf2f(c.y & 0xffffu)) * inv;
  float x3 = (bf2f(a.y >> 16)     + bf2f(c.y >> 16))     * inv;
  uint2 o;
  o.x = cvt_pk_bf16(x0, x1);
  o.y = cvt_pk_bf16(x2, x3);
  ((uint2*)(ctx + (size_t)m * 1024))[t] = o;
}

// ---- residual + LayerNorm (proj = two bf16 K-split partials) ----------------

__global__ __launch_bounds__(256)
void ln_kernel(const float* __restrict__ resid, const ushort_t* __restrict__ p0,
               const ushort_t* __restrict__ p1,
               const float* __restrict__ gamma, const float* __restrict__ beta,
               float* __restrict__ out) {
  int m = blockIdx.x;
  int t = threadIdx.x;
  int lane = t & 63, wave = t >> 6;
  float4 a = ((const float4*)(resid + (size_t)m * 1024))[t];
  uint2 v0 = ((const uint2*)(p0 + (size_t)m * 1024))[t];
  uint2 v1 = ((const uint2*)(p1 + (size_t)m * 1024))[t];
  float4 x;
  x.x = a.x + bf2f(v0.x & 0xffffu) + bf2f(v1.x & 0xffffu);
  x.y = a.y + bf2f(v0.x >> 16)     + bf2f(v1.x >> 16);
  x.z = a.z + bf2f(v0.y & 0xffffu) + bf2f(v1.y & 0xffffu);
  x.w = a.w + bf2f(v0.y >> 16)     + bf2f(v1.y >> 16);
  float sum = (x.x + x.y) + (x.z + x.w);
  float ssq = x.x * x.x + x.y * x.y + x.z * x.z + x.w * x.w;
  for (int off = 1; off < 64; off <<= 1) {
    sum += __shfl_xor(sum, off);
    ssq += __shfl_xor(ssq, off);
  }
  __shared__ float red[8];
  if (lane == 0) { red[wave] = sum; red[4 + wave] = ssq; }
  __syncthreads();
  sum = red[0] + red[1] + red[2] + red[3];
  ssq = red[4] + red[5] + red[6] + red[7];
  float mu = sum * (1.f / 1024.f);
  float var = ssq * (1.f / 1024.f) - mu * mu;
  float rstd = rsqrtf(var + 1e-5f);
  const float4* gp = (const float4*)gamma;
  const float4* bp = (const float4*)beta;
  float4 gg = gp[t], bb = bp[t];
  float4 y;
  y.x = (x.x - mu) * rstd * gg.x + bb.x;
  y.y = (x.y - mu) * rstd * gg.y + bb.y;
  y.z = (x.z - mu) * rstd * gg.z + bb.z;
  y.w = (x.w - mu) * rstd * gg.w + bb.w;
  ((float4*)(out + (size_t)m * 1024))[t] = y;
}

// ---- launch ----------------------------------------------------------------

extern "C" void kernel_launch(void* const* d_in, const int* in_sizes, int n_in,
                              void* d_out, int out_size, void* d_ws, size_t ws_size,
                              hipStream_t stream) {
  (void)in_sizes; (void)n_in; (void)out_size; (void)ws_size;
  const float* query = (const float*)d_in[0];
  const float* keyi  = (const float*)d_in[1];
  const float* value = (const float*)d_in[2];
  const float* w_q = (const float*)d_in[3];
  const float* w_k = (const float*)d_in[4];
  const float* w_v = (const float*)d_in[5];
  const float* w_o = (const float*)d_in[6];
  const float* ln_g = (const float*)d_in[7];
  const float* ln_b = (const float*)d_in[8];

  char* ws = (char*)d_ws;
  const size_t MB = 1u << 20;
  // workspace (X buffers no longer exist — conversion fused into QKV GEMM):
  //   phase 2: op0(0-8) op1(8-16) l0(16MB) l1(17MB)
  //   phase 3: proj0(0-8) proj1(8-16)
  ushort_t* op0 = (ushort_t*)(ws + 0 * MB);
  ushort_t* op1 = (ushort_t*)(ws + 8 * MB);
  float*    l0  = (float*)   (ws + 16 * MB);
  float*    l1  = (float*)   (ws + 17 * MB);
  ushort_t* proj0 = (ushort_t*)(ws + 0 * MB);
  ushort_t* proj1 = (ushort_t*)(ws + 8 * MB);
  ushort_t* Wq  = (ushort_t*)(ws + 24 * MB);
  ushort_t* Wk  = (ushort_t*)(ws + 26 * MB);
  ushort_t* Wv  = (ushort_t*)(ws + 28 * MB);
  ushort_t* Wo  = (ushort_t*)(ws + 30 * MB);
  ushort_t* Qh  = (ushort_t*)(ws + 32 * MB);
  ushort_t* Kh  = (ushort_t*)(ws + 40 * MB);
  ushort_t* Vt  = (ushort_t*)(ws + 48 * MB);
  ushort_t* ctx = (ushort_t*)(ws + 56 * MB);

  const float SCL = 0.18033688f;  // (1/sqrt(64)) * log2(e), folded into Q

  cvt_w_kernel<<<dim3(512, 4), 256, 0, stream>>>(w_q, w_k, w_v, w_o,
                                                 Wq, Wk, Wv, Wo);

  // QKV with fused f32->bf16 on the X operand (dbuf drain template):
  //   z=0 Q (A=query f32, W=Wq), z=1 K (A=key f32, W=Wk),
  //   z=2 V^T (A=Wv bf16, W=value f32; grid roles swapped)
  gemm128<<<dim3(32, 8, 3), 256, 0, stream>>>(query, keyi, Wv,
                                              Wq, Wk, value,
                                              Qh, Kh, Vt, 0, 16, SCL);
  // attention: KV-split x2, XCD-local heads -> unnormalized partials
  attn_kernel<<<dim3(32, 16, 2), 256, 0, stream>>>(Qh, Kh, Vt,
                                                   op0, op1, l0, l1);
  attn_reduce<<<4096, 256, 0, stream>>>(op0, op1, l0, l1, ctx);
  // O projection: K-split x2 (z = k-half), bf16 partials, transposed grid
  gemm128<<<dim3(32, 8, 2), 256, 0, stream>>>(ctx, ctx, ctx, Wo, Wo, Wo,
                                              proj0, proj1, proj0, 3, 8, 1.0f);
  ln_kernel<<<4096, 256, 0, stream>>>(query, proj0, proj1, ln_g, ln_b,
                                      (float*)d_out);
}

// Round 20
// 123.870 us; speedup vs baseline: 1.0406x; 1.0406x over previous
//
#include <hip/hip_runtime.h>
#include <hip/hip_bf16.h>

#define DEVI __device__ __forceinline__

typedef float f32x4 __attribute__((ext_vector_type(4)));
typedef short bf16x8 __attribute__((ext_vector_type(8)));
typedef unsigned short ushort_t;

DEVI ushort_t f2bf(float x) {
  union { float f; unsigned u; } c; c.f = x;
  unsigned u = c.u;
  unsigned r = (u + 0x7fffu + ((u >> 16) & 1u)) >> 16;  // RNE
  return (ushort_t)r;
}

DEVI float bf2f(unsigned hw) {
  union { unsigned u; float f; } c; c.u = hw << 16; return c.f;
}

DEVI unsigned cvt_pk_bf16(float lo, float hi) {
  unsigned r;
  asm volatile("v_cvt_pk_bf16_f32 %0, %1, %2" : "=v"(r) : "v"(lo), "v"(hi));
  return r;
}

DEVI void gload16(const ushort_t* g, ushort_t* l) {
  __builtin_amdgcn_global_load_lds(
      (const __attribute__((address_space(1))) unsigned int*)g,
      (__attribute__((address_space(3))) unsigned int*)l, 16, 0, 0);
}

// ---- f32 -> bf16 conversion, weights only (X is fused into QKV GEMM) -------

__global__ __launch_bounds__(256)
void cvt_w_kernel(const float* __restrict__ w0, const float* __restrict__ w1,
                  const float* __restrict__ w2, const float* __restrict__ w3,
                  ushort_t* __restrict__ q0, ushort_t* __restrict__ q1,
                  ushort_t* __restrict__ q2, ushort_t* __restrict__ q3) {
  int i = blockIdx.x * 256 + threadIdx.x;       // < 524288 (4 x 131072 n8)
  int w = i >> 17;
  int local = i & 131071;
  const float* in = (w == 0) ? w0 : (w == 1) ? w1 : (w == 2) ? w2 : w3;
  ushort_t* out = (w == 0) ? q0 : (w == 1) ? q1 : (w == 2) ? q2 : q3;
  const float4* p = (const float4*)in + (size_t)local * 2;
  float4 a = p[0], b = p[1];
  uint4 v;
  v.x = cvt_pk_bf16(a.x, a.y);
  v.y = cvt_pk_bf16(a.z, a.w);
  v.z = cvt_pk_bf16(b.x, b.y);
  v.w = cvt_pk_bf16(b.z, b.w);
  ((uint4*)out)[local] = v;
}

// ---- unified 128x128 GEMM: C[m][n] = sum_k A[m,k] * W[n,k] -----------------
// m97 SINGLE-buffer, transposed grid (x = big-operand panel -> XCD-local
// sharing). One operand may be f32 in HBM (modes 0/1: A = query/key; mode 2:
// W = value): reg-staged ONE TILE AHEAD (FLOAD issued right after sync#1,
// overlapping compute), converted with cvt_pk + ds_write_b128 producing the
// IDENTICAL LDS image as gload16 (LDS[row][c] = g[row][c^(row&7)]). All LDS
// writes precede sync#1; all reads precede sync#2 — race-screened drain
// template (round 18, best measured). mode 3 = O-proj K-split half.

__global__ __launch_bounds__(256)
void gemm128(const void* A0v, const void* A1v, const void* A2v,
             const void* W0v, const void* W1v, const void* W2v,
             void* __restrict__ O0, void* __restrict__ O1,
             void* __restrict__ O2, int mode_base, int nsteps, float qscale) {
  constexpr int K = 1024;
  int z = blockIdx.z;
  int mode = (mode_base == 3) ? 3 : mode_base + z;
  const void* Av = (z == 0) ? A0v : (z == 1) ? A1v : A2v;
  const void* Wv = (z == 0) ? W0v : (z == 1) ? W1v : W2v;
  void* Op = (z == 0) ? O0 : (z == 1) ? O1 : O2;
  if (mode == 3) {           // K-split: z picks the k-window, own partial buf
    Av = (const ushort_t*)A0v + z * 512;
    Wv = (const ushort_t*)W0v + z * 512;
    Op = z ? O1 : O0;
  }
  bool aF32 = (mode <= 1);   // block-uniform
  bool bF32 = (mode == 2);
  bool fused = aF32 || bF32;
  float scale = (mode == 0) ? qscale : 1.0f;
  // transposed mapping: x = big-operand panel, y = weight panel
  int m0 = (mode == 2) ? blockIdx.y * 128 : blockIdx.x * 128;
  int n0 = (mode == 2) ? blockIdx.x * 128 : blockIdx.y * 128;

  __shared__ __align__(16) ushort_t Asm[128 * 64];
  __shared__ __align__(16) ushort_t Bsm[128 * 64];

  int t = threadIdx.x;
  int lane = t & 63, wave = t >> 6;
  int wm = wave >> 1, wn = wave & 1;
  int col = lane & 15, g = lane >> 4;
  int lr = lane >> 3, lc = lane & 7;
  int cswz = col & 7;

  int rowA = m0 + wave * 32 + lr;
  int rowB = n0 + wave * 32 + lr;
  const ushort_t* aSrcB = (const ushort_t*)Av + (size_t)rowA * K + (lc ^ lr) * 8;
  const ushort_t* bSrcB = (const ushort_t*)Wv + (size_t)rowB * K + (lc ^ lr) * 8;
  // f32 side: read global chunk (lc^lr), write LDS chunk lc -> same image
  const float* fSrc = aF32
      ? ((const float*)Av + (size_t)rowA * K + (lc ^ lr) * 8)
      : ((const float*)Wv + (size_t)rowB * K + (lc ^ lr) * 8);
  ushort_t* fDst = aF32 ? Asm : Bsm;
  int fOffBase = (wave * 32 + lr) * 64 + lc * 8;

  f32x4 z4 = {0.f, 0.f, 0.f, 0.f};
  f32x4 acc[4][4];
  for (int i = 0; i < 4; i++)
    for (int j = 0; j < 4; j++) acc[i][j] = z4;

  float4 fr[4][2];

#define FLOAD(koff) do {                                                   \
    _Pragma("unroll")                                                      \
    for (int i_ = 0; i_ < 4; i_++) {                                       \
      const float* p_ = fSrc + (size_t)(i_ * 8) * K + (koff);              \
      fr[i_][0] = *(const float4*)p_;                                      \
      fr[i_][1] = *(const float4*)(p_ + 4);                                \
    }                                                                      \
  } while (0)

#define FWRITE() do {                                                      \
    _Pragma("unroll")                                                      \
    for (int i_ = 0; i_ < 4; i_++) {                                       \
      uint4 w_;                                                            \
      w_.x = cvt_pk_bf16(fr[i_][0].x, fr[i_][0].y);                        \
      w_.y = cvt_pk_bf16(fr[i_][0].z, fr[i_][0].w);                        \
      w_.z = cvt_pk_bf16(fr[i_][1].x, fr[i_][1].y);                        \
      w_.w = cvt_pk_bf16(fr[i_][1].z, fr[i_][1].w);                        \
      *(uint4*)(fDst + fOffBase + i_ * 8 * 64) = w_;                       \
    }                                                                      \
  } while (0)

  if (fused) FLOAD(0);

  for (int kt = 0; kt < nsteps; ++kt) {
    int koff = kt * 64;
    if (fused) FWRITE();               // publish tile kt (f32 side)
    if (!aF32) {
#pragma unroll
      for (int i_ = 0; i_ < 4; i_++)
        gload16(aSrcB + koff + i_ * 8 * K, &Asm[(wave * 32 + i_ * 8) * 64]);
    }
    if (!bF32) {
#pragma unroll
      for (int i_ = 0; i_ < 4; i_++)
        gload16(bSrcB + koff + i_ * 8 * K, &Bsm[(wave * 32 + i_ * 8) * 64]);
    }
    __syncthreads();                   // drain vmcnt+lgkm: tile kt ready
    if (fused && kt + 1 < nsteps) FLOAD(koff + 64);  // overlaps compute
#pragma unroll
    for (int kk = 0; kk < 2; ++kk) {
      bf16x8 af[4], bfr[4];
#pragma unroll
      for (int mi = 0; mi < 4; mi++) {
        int row = wm * 64 + mi * 16 + col;
        af[mi] = *(const bf16x8*)(Asm + row * 64 + (((kk * 4 + g) ^ cswz) * 8));
      }
#pragma unroll
      for (int ni = 0; ni < 4; ni++) {
        int row = wn * 64 + ni * 16 + col;
        bfr[ni] = *(const bf16x8*)(Bsm + row * 64 + (((kk * 4 + g) ^ cswz) * 8));
      }
      __builtin_amdgcn_s_setprio(1);
#pragma unroll
      for (int mi = 0; mi < 4; mi++)
#pragma unroll
        for (int ni = 0; ni < 4; ni++)
          acc[mi][ni] = __builtin_amdgcn_mfma_f32_16x16x32_bf16(af[mi], bfr[ni],
                                                                acc[mi][ni], 0, 0, 0);
      __builtin_amdgcn_s_setprio(0);
    }
    __syncthreads();                   // all reads done before next writes
  }

  // epilogue: C row m = m0+wm*64+mi*16+g*4+r, col n = n0+wn*64+ni*16+col
#pragma unroll
  for (int mi = 0; mi < 4; mi++)
#pragma unroll
    for (int ni = 0; ni < 4; ni++)
#pragma unroll
      for (int r = 0; r < 4; r++) {
        int m = m0 + wm * 64 + mi * 16 + g * 4 + r;
        int n = n0 + wn * 64 + ni * 16 + col;
        float v = acc[mi][ni][r] * scale;
        if (mode <= 1) {          // [B,H,S,64]: m=token, n=h*64+d
          int b = m >> 11, s = m & 2047, h = n >> 6, d = n & 63;
          ((ushort_t*)Op)[(((size_t)(b * 16 + h) * 2048 + s) * 64) + d] = f2bf(v);
        } else if (mode == 2) {   // V^T [B,H,64,S]: m=h*64+d, n=token
          int h = m >> 6, d = m & 63, b = n >> 11, s = n & 2047;
          ((ushort_t*)Op)[(((size_t)(b * 16 + h) * 64 + d) * 2048) + s] = f2bf(v);
        } else {                  // bf16 partial [M,1024]
          ((ushort_t*)Op)[(size_t)m * 1024 + n] = f2bf(v);
        }
      }
#undef FLOAD
#undef FWRITE
}

// ---- flash attention — KV-split x2, permuted-K staging, lane-local P --------
// (256,3), XCD-co-located heads, packed 4B epilogue — best measured (44.5us).

__global__ __launch_bounds__(256, 3)
void attn_kernel(const ushort_t* __restrict__ Qh, const ushort_t* __restrict__ Kh,
                 const ushort_t* __restrict__ Vt,
                 ushort_t* __restrict__ op0, ushort_t* __restrict__ op1,
                 float* __restrict__ lp0, float* __restrict__ lp1) {
  int bh = blockIdx.x;   // b*16+h  (XCD-co-located)
  int qt = blockIdx.y;   // q tile of 128
  int sp = blockIdx.z;   // key split (0: keys 0..1023, 1: 1024..2047)
  int t = threadIdx.x, lane = t & 63, wave = t >> 6;
  int col = lane & 15, g = lane >> 4;
  int lr = lane >> 3, lc = lane & 7;
  int cswz = col & 7;
  int q0 = qt * 128 + wave * 32;
  int kbase = sp * 1024;
  ushort_t* opart = sp ? op1 : op0;
  float* lpart = sp ? lp1 : lp0;

  const ushort_t* Qp = Qh + (size_t)bh * 2048 * 64;
  const ushort_t* Kp = Kh + (size_t)bh * 2048 * 64;
  const ushort_t* Vp = Vt + (size_t)bh * 64 * 2048;  // [64 d][2048 k]

  __shared__ __align__(16) ushort_t Ksm[2][64 * 64];
  __shared__ __align__(16) ushort_t Vsm[2][64 * 64];

  // K row permutation: slot -> key (bits: s=a<<5|b<<4|g<<2|r -> a<<5|g<<3|b<<2|r)
  int slot0 = wave * 16 + lr;
  int slot1 = slot0 + 8;
  int key0 = (slot0 & 0x20) | ((slot0 & 0x0C) << 1) | ((slot0 & 0x10) >> 2) | (slot0 & 3);
  int key1 = (slot1 & 0x20) | ((slot1 & 0x0C) << 1) | ((slot1 & 0x10) >> 2) | (slot1 & 3);

  const ushort_t* kSrc0 = Kp + (size_t)key0 * 64 + (lc ^ lr) * 8;
  const ushort_t* kSrc1 = Kp + (size_t)key1 * 64 + (lc ^ lr) * 8;
  const ushort_t* vSrc = Vp + (size_t)(wave * 16 + lr) * 2048 + (lc ^ lr) * 8;

#define ATTN_STAGE(buf, k0) do { \
    gload16(kSrc0 + (size_t)(k0) * 64, &Ksm[buf][wave * 1024]);        \
    gload16(kSrc1 + (size_t)(k0) * 64, &Ksm[buf][wave * 1024 + 512]);  \
    gload16(vSrc + (k0),               &Vsm[buf][wave * 1024]);        \
    gload16(vSrc + (k0) + 16384,       &Vsm[buf][wave * 1024 + 512]);  \
  } while (0)

  bf16x8 qa0 = *(const bf16x8*)(Qp + (size_t)(q0 + col) * 64 + g * 8);
  bf16x8 qa1 = *(const bf16x8*)(Qp + (size_t)(q0 + col) * 64 + 32 + g * 8);
  bf16x8 qb0 = *(const bf16x8*)(Qp + (size_t)(q0 + 16 + col) * 64 + g * 8);
  bf16x8 qb1 = *(const bf16x8*)(Qp + (size_t)(q0 + 16 + col) * 64 + 32 + g * 8);

  f32x4 z4 = {0.f, 0.f, 0.f, 0.f};
  f32x4 oa[4], ob[4];
  for (int i = 0; i < 4; i++) { oa[i] = z4; ob[i] = z4; }
  f32x4 la = z4, lb = z4;   // per-lane partial denominators

  ATTN_STAGE(0, kbase);
  __syncthreads();                       // buf0 ready

  for (int it = 0; it < 16; ++it) {
    int cur = it & 1;
    int k0 = kbase + it * 64;
    if (it < 15) ATTN_STAGE(cur ^ 1, k0 + 64);  // prefetch next tile

    const ushort_t* Ks = Ksm[cur];
    const ushort_t* Vs = Vsm[cur];

    // QK^T (swapped): sX[kt][r] = exp2-domain score(slot = kt*16+4g+r, q)
    f32x4 sa[4], sb[4];
#pragma unroll
    for (int kt = 0; kt < 4; kt++) {
      int off = (kt * 16 + col) * 64 + ((g ^ cswz) * 8);
      bf16x8 kf0 = *(const bf16x8*)(Ks + off);
      bf16x8 kf1 = *(const bf16x8*)(Ks + (off ^ 32));
      f32x4 a = z4, b = z4;
      __builtin_amdgcn_s_setprio(1);
      a = __builtin_amdgcn_mfma_f32_16x16x32_bf16(kf0, qa0, a, 0, 0, 0);
      a = __builtin_amdgcn_mfma_f32_16x16x32_bf16(kf1, qa1, a, 0, 0, 0);
      b = __builtin_amdgcn_mfma_f32_16x16x32_bf16(kf0, qb0, b, 0, 0, 0);
      b = __builtin_amdgcn_mfma_f32_16x16x32_bf16(kf1, qb1, b, 0, 0, 0);
      __builtin_amdgcn_s_setprio(0);
      sa[kt] = a; sb[kt] = b;
    }

    // exp2 numerators; packed u32s are, in order, exactly the PV B-fragments
    unsigned pka[8], pkb[8];
#pragma unroll
    for (int kt = 0; kt < 4; kt++) {
      float a0 = __builtin_amdgcn_exp2f(sa[kt][0]);
      float a1 = __builtin_amdgcn_exp2f(sa[kt][1]);
      float a2 = __builtin_amdgcn_exp2f(sa[kt][2]);
      float a3 = __builtin_amdgcn_exp2f(sa[kt][3]);
      la[0] += a0; la[1] += a1; la[2] += a2; la[3] += a3;
      pka[2 * kt]     = cvt_pk_bf16(a0, a1);
      pka[2 * kt + 1] = cvt_pk_bf16(a2, a3);
      float b0 = __builtin_amdgcn_exp2f(sb[kt][0]);
      float b1 = __builtin_amdgcn_exp2f(sb[kt][1]);
      float b2 = __builtin_amdgcn_exp2f(sb[kt][2]);
      float b3 = __builtin_amdgcn_exp2f(sb[kt][3]);
      lb[0] += b0; lb[1] += b1; lb[2] += b2; lb[3] += b3;
      pkb[2 * kt]     = cvt_pk_bf16(b0, b1);
      pkb[2 * kt + 1] = cvt_pk_bf16(b2, b3);
    }

    // PV: O^T += mfma(V^T, P^T), P fragment straight from registers
#pragma unroll
    for (int kk = 0; kk < 2; kk++) {
      union { uint4 u; bf16x8 f; } ua, ub;
      ua.u.x = pka[4 * kk];     ua.u.y = pka[4 * kk + 1];
      ua.u.z = pka[4 * kk + 2]; ua.u.w = pka[4 * kk + 3];
      ub.u.x = pkb[4 * kk];     ub.u.y = pkb[4 * kk + 1];
      ub.u.z = pkb[4 * kk + 2]; ub.u.w = pkb[4 * kk + 3];
      __builtin_amdgcn_s_setprio(1);
#pragma unroll
      for (int dt = 0; dt < 4; dt++) {
        bf16x8 vf = *(const bf16x8*)(Vs + (dt * 16 + col) * 64 +
                                     (((kk * 4 + g) ^ cswz) * 8));
        oa[dt] = __builtin_amdgcn_mfma_f32_16x16x32_bf16(vf, ua.f, oa[dt], 0, 0, 0);
        ob[dt] = __builtin_amdgcn_mfma_f32_16x16x32_bf16(vf, ub.f, ob[dt], 0, 0, 0);
      }
      __builtin_amdgcn_s_setprio(0);
    }
    __syncthreads();   // drains vmcnt(0) (next K/V buf written) + lgkm; fence
  }
#undef ATTN_STAGE

  float lva = (la[0] + la[1]) + (la[2] + la[3]);
  lva += __shfl_xor(lva, 16);
  lva += __shfl_xor(lva, 32);
  float lvb = (lb[0] + lb[1]) + (lb[2] + lb[3]);
  lvb += __shfl_xor(lvb, 16);
  lvb += __shfl_xor(lvb, 32);
  if (g == 0) {                                 // lanes 0..15 write l
    lpart[(size_t)bh * 2048 + q0 + col] = lva;
    lpart[(size_t)bh * 2048 + q0 + 16 + col] = lvb;
  }
  int b = bh >> 4, h = bh & 15;
  // packed epilogue: d pairs -> one 4B store
#pragma unroll
  for (int dt = 0; dt < 4; dt++)
#pragma unroll
    for (int rp = 0; rp < 2; rp++) {
      int d = dt * 16 + g * 4 + rp * 2;
      unsigned pa = cvt_pk_bf16(oa[dt][rp * 2], oa[dt][rp * 2 + 1]);
      unsigned pb = cvt_pk_bf16(ob[dt][rp * 2], ob[dt][rp * 2 + 1]);
      *(unsigned*)(opart + ((size_t)(b * 2048 + q0 + col)) * 1024 + h * 64 + d) = pa;
      *(unsigned*)(opart + ((size_t)(b * 2048 + q0 + 16 + col)) * 1024 + h * 64 + d) = pb;
    }
}

// ---- attn partial combine: ctx = (o0 + o1) / (l0 + l1) ---------------------

__global__ __launch_bounds__(256)
void attn_reduce(const ushort_t* __restrict__ o0, const ushort_t* __restrict__ o1,
                 const float* __restrict__ l0, const float* __restrict__ l1,
                 ushort_t* __restrict__ ctx) {
  int m = blockIdx.x;                  // token 0..4095
  int t = threadIdx.x;                 // 4 bf16 elems each
  int b = m >> 11, q = m & 2047;
  int h = t >> 4;                      // (t*4) >> 6
  size_t li = (size_t)(b * 16 + h) * 2048 + q;
  float inv = 1.0f / (l0[li] + l1[li]);
  uint2 a = ((const uint2*)(o0 + (size_t)m * 1024))[t];
  uint2 c = ((const uint2*)(o1 + (size_t)m * 1024))[t];
  float x0 = (bf2f(a.x & 0xffffu) + bf2f(c.x & 0xffffu)) * inv;
  float x1 = (bf2f(a.x >> 16)     + bf2f(c.x >> 16))     * inv;
  float x2 = (bf2f(a.y & 0xffffu) + bf2f(c.y & 0xffffu)) * inv;
  float x3 = (bf2f(a.y >> 16)     + bf2f(c.y >> 16))     * inv;
  uint2 o;
  o.x = cvt_pk_bf16(x0, x1);
  o.y = cvt_pk_bf16(x2, x3);
  ((uint2*)(ctx + (size_t)m * 1024))[t] = o;
}

// ---- residual + LayerNorm (proj = two bf16 K-split partials) ----------------

__global__ __launch_bounds__(256)
void ln_kernel(const float* __restrict__ resid, const ushort_t* __restrict__ p0,
               const ushort_t* __restrict__ p1,
               const float* __restrict__ gamma, const float* __restrict__ beta,
               float* __restrict__ out) {
  int m = blockIdx.x;
  int t = threadIdx.x;
  int lane = t & 63, wave = t >> 6;
  float4 a = ((const float4*)(resid + (size_t)m * 1024))[t];
  uint2 v0 = ((const uint2*)(p0 + (size_t)m * 1024))[t];
  uint2 v1 = ((const uint2*)(p1 + (size_t)m * 1024))[t];
  float4 x;
  x.x = a.x + bf2f(v0.x & 0xffffu) + bf2f(v1.x & 0xffffu);
  x.y = a.y + bf2f(v0.x >> 16)     + bf2f(v1.x >> 16);
  x.z = a.z + bf2f(v0.y & 0xffffu) + bf2f(v1.y & 0xffffu);
  x.w = a.w + bf2f(v0.y >> 16)     + bf2f(v1.y >> 16);
  float sum = (x.x + x.y) + (x.z + x.w);
  float ssq = x.x * x.x + x.y * x.y + x.z * x.z + x.w * x.w;
  for (int off = 1; off < 64; off <<= 1) {
    sum += __shfl_xor(sum, off);
    ssq += __shfl_xor(ssq, off);
  }
  __shared__ float red[8];
  if (lane == 0) { red[wave] = sum; red[4 + wave] = ssq; }
  __syncthreads();
  sum = red[0] + red[1] + red[2] + red[3];
  ssq = red[4] + red[5] + red[6] + red[7];
  float mu = sum * (1.f / 1024.f);
  float var = ssq * (1.f / 1024.f) - mu * mu;
  float rstd = rsqrtf(var + 1e-5f);
  const float4* gp = (const float4*)gamma;
  const float4* bp = (const float4*)beta;
  float4 gg = gp[t], bb = bp[t];
  float4 y;
  y.x = (x.x - mu) * rstd * gg.x + bb.x;
  y.y = (x.y - mu) * rstd * gg.y + bb.y;
  y.z = (x.z - mu) * rstd * gg.z + bb.z;
  y.w = (x.w - mu) * rstd * gg.w + bb.w;
  ((float4*)(out + (size_t)m * 1024))[t] = y;
}

// ---- launch ----------------------------------------------------------------

extern "C" void kernel_launch(void* const* d_in, const int* in_sizes, int n_in,
                              void* d_out, int out_size, void* d_ws, size_t ws_size,
                              hipStream_t stream) {
  (void)in_sizes; (void)n_in; (void)out_size; (void)ws_size;
  const float* query = (const float*)d_in[0];
  const float* keyi  = (const float*)d_in[1];
  const float* value = (const float*)d_in[2];
  const float* w_q = (const float*)d_in[3];
  const float* w_k = (const float*)d_in[4];
  const float* w_v = (const float*)d_in[5];
  const float* w_o = (const float*)d_in[6];
  const float* ln_g = (const float*)d_in[7];
  const float* ln_b = (const float*)d_in[8];

  char* ws = (char*)d_ws;
  const size_t MB = 1u << 20;
  // workspace (X buffers no longer exist — conversion fused into QKV GEMM):
  //   phase 2: op0(0-8) op1(8-16) l0(16MB) l1(17MB)
  //   phase 3: proj0(0-8) proj1(8-16)
  ushort_t* op0 = (ushort_t*)(ws + 0 * MB);
  ushort_t* op1 = (ushort_t*)(ws + 8 * MB);
  float*    l0  = (float*)   (ws + 16 * MB);
  float*    l1  = (float*)   (ws + 17 * MB);
  ushort_t* proj0 = (ushort_t*)(ws + 0 * MB);
  ushort_t* proj1 = (ushort_t*)(ws + 8 * MB);
  ushort_t* Wq  = (ushort_t*)(ws + 24 * MB);
  ushort_t* Wk  = (ushort_t*)(ws + 26 * MB);
  ushort_t* Wv  = (ushort_t*)(ws + 28 * MB);
  ushort_t* Wo  = (ushort_t*)(ws + 30 * MB);
  ushort_t* Qh  = (ushort_t*)(ws + 32 * MB);
  ushort_t* Kh  = (ushort_t*)(ws + 40 * MB);
  ushort_t* Vt  = (ushort_t*)(ws + 48 * MB);
  ushort_t* ctx = (ushort_t*)(ws + 56 * MB);

  const float SCL = 0.18033688f;  // (1/sqrt(64)) * log2(e), folded into Q

  cvt_w_kernel<<<2048, 256, 0, stream>>>(w_q, w_k, w_v, w_o,
                                         Wq, Wk, Wv, Wo);

  // QKV with fused f32->bf16 on the X operand (single-buffer, round-18 best):
  //   z=0 Q (A=query f32, W=Wq), z=1 K (A=key f32, W=Wk),
  //   z=2 V^T (A=Wv bf16, W=value f32; grid roles swapped)
  gemm128<<<dim3(32, 8, 3), 256, 0, stream>>>(query, keyi, Wv,
                                              Wq, Wk, value,
                                              Qh, Kh, Vt, 0, 16, SCL);
  // attention: KV-split x2, XCD-local heads -> unnormalized partials
  attn_kernel<<<dim3(32, 16, 2), 256, 0, stream>>>(Qh, Kh, Vt,
                                                   op0, op1, l0, l1);
  attn_reduce<<<4096, 256, 0, stream>>>(op0, op1, l0, l1, ctx);
  // O projection: K-split x2 (z = k-half), bf16 partials, transposed grid
  gemm128<<<dim3(32, 8, 2), 256, 0, stream>>>(ctx, ctx, ctx, Wo, Wo, Wo,
                                              proj0, proj1, proj0, 3, 8, 1.0f);
  ln_kernel<<<4096, 256, 0, stream>>>(query, proj0, proj1, ln_g, ln_b,
                                      (float*)d_out);
}